// Round 1
// baseline (1006.801 us; speedup 1.0000x reference)
//
#include <hip/hip_runtime.h>
#include <hip/hip_bf16.h>
#include <math.h>

// MoE top-2 of 8 experts. D_MODEL=1024, D_FF=4096, tokens = 2*2048 = 4096.
// Inputs (fp32): x[4096][1024], gate_w[8][1024], gate_b[8],
//                w1[8][1024][4096], b1[8][4096], w2[8][4096][1024], b2[8][1024]
// Output: out[4096][1024] fp32 then loss scalar at flat index 4096*1024.
//
// Pipeline: router -> prefix/loss -> (W1 transpose->bf16) -> GEMM1(gather,gelu)->H
//           -> (W2 transpose->bf16, reusing same ws buffer) -> GEMM2 -> atomic scatter.
// Workspace use ~134.5 MB.

#define D_MODEL 1024
#define D_FF    4096
#define NE      8
#define NTOK    4096
#define CAP     4096   // per-expert capacity (max possible = NTOK)

typedef __attribute__((ext_vector_type(4))) float f32x4;
typedef __attribute__((ext_vector_type(8))) short s16x8;

__device__ __forceinline__ short f2bf(float f) {
    union { float f; unsigned u; } v; v.f = f;
    unsigned r = v.u + 0x7FFFu + ((v.u >> 16) & 1u);  // RNE
    return (short)(r >> 16);
}

__device__ __forceinline__ s16x8 cvt8(f32x4 a, f32x4 b) {
    s16x8 r;
    r[0]=f2bf(a[0]); r[1]=f2bf(a[1]); r[2]=f2bf(a[2]); r[3]=f2bf(a[3]);
    r[4]=f2bf(b[0]); r[5]=f2bf(b[1]); r[6]=f2bf(b[2]); r[7]=f2bf(b[3]);
    return r;
}

// ---------------- Router: one wave (64 lanes) per token ----------------
__global__ __launch_bounds__(64) void router_kernel(
    const float* __restrict__ x, const float* __restrict__ gw,
    const float* __restrict__ gb,
    int* __restrict__ cnt, float* __restrict__ usage,
    int* __restrict__ tok_list, float* __restrict__ wt_list)
{
    int t = blockIdx.x;
    int lane = threadIdx.x;
    const float* xr = x + (size_t)t * D_MODEL;

    float acc[NE];
#pragma unroll
    for (int e = 0; e < NE; e++) acc[e] = 0.f;

    for (int i = lane * 4; i < D_MODEL; i += 64 * 4) {
        f32x4 xv = *(const f32x4*)(xr + i);
#pragma unroll
        for (int e = 0; e < NE; e++) {
            f32x4 gv = *(const f32x4*)(gw + e * D_MODEL + i);
            acc[e] += xv[0]*gv[0] + xv[1]*gv[1] + xv[2]*gv[2] + xv[3]*gv[3];
        }
    }
#pragma unroll
    for (int e = 0; e < NE; e++) {
        float a = acc[e];
        for (int off = 32; off; off >>= 1) a += __shfl_down(a, off);
        acc[e] = a;
    }
    if (lane == 0) {
        float logits[NE];
        float mx = -1e30f;
#pragma unroll
        for (int e = 0; e < NE; e++) { logits[e] = acc[e] + gb[e]; mx = fmaxf(mx, logits[e]); }
        float pe[NE]; float se = 0.f;
#pragma unroll
        for (int e = 0; e < NE; e++) { pe[e] = expf(logits[e] - mx); se += pe[e]; }
        float inv = 1.f / se;
#pragma unroll
        for (int e = 0; e < NE; e++) atomicAdd(&usage[e], pe[e] * inv);
        // top-2 (ties -> lower index, matches lax.top_k)
        int i0 = 0;
#pragma unroll
        for (int e = 1; e < NE; e++) if (logits[e] > logits[i0]) i0 = e;
        int i1 = -1;
#pragma unroll
        for (int e = 0; e < NE; e++) {
            if (e == i0) continue;
            if (i1 < 0 || logits[e] > logits[i1]) i1 = e;
        }
        float w0 = 1.f / (1.f + expf(logits[i1] - logits[i0]));
        float w1 = 1.f - w0;
        int p0 = atomicAdd(&cnt[i0], 1);
        tok_list[i0 * CAP + p0] = t; wt_list[i0 * CAP + p0] = w0;
        int p1 = atomicAdd(&cnt[i1], 1);
        tok_list[i1 * CAP + p1] = t; wt_list[i1 * CAP + p1] = w1;
    }
}

// ---------------- prefix offsets + load-balancing loss ----------------
__global__ void finalize_router(const int* __restrict__ cnt,
                                const float* __restrict__ usage,
                                int* __restrict__ offsets,
                                float* __restrict__ out_loss)
{
    int o = 0;
    for (int e = 0; e < NE; e++) { offsets[e] = o; o += cnt[e]; }
    float s = 0.f;
    for (int e = 0; e < NE; e++) { float u = usage[e] / (float)NTOK; s += u * u; }
    *out_loss = (float)NE * s - 1.f;
}

// ---------------- transpose + fp32->bf16: src[R][C] -> dst[C][R], per expert z ----------------
__global__ __launch_bounds__(256) void transpose_cvt(
    const float* __restrict__ src, short* __restrict__ dst, int R, int C)
{
    __shared__ float tile[32][33];
    int e = blockIdx.z;
    src += (size_t)e * R * C;
    dst += (size_t)e * R * C;
    int c0 = blockIdx.x * 32, r0 = blockIdx.y * 32;
    int tx = threadIdx.x, ty = threadIdx.y;   // 32 x 8
#pragma unroll
    for (int j = 0; j < 4; j++)
        tile[ty * 4 + j][tx] = src[(size_t)(r0 + ty * 4 + j) * C + c0 + tx];
    __syncthreads();
#pragma unroll
    for (int j = 0; j < 4; j++)
        dst[(size_t)(c0 + ty * 4 + j) * R + r0 + tx] = f2bf(tile[tx][ty * 4 + j]);
}

// ---------------- GEMM1: H[slot][f] = gelu( x[tok] @ W1[e] + b1[e] ), bf16 out ----------------
// A: gathered x rows (fp32 -> bf16 on stage). B: W1T[e][f][k] bf16. 64x64 tile, BK=32.
__global__ __launch_bounds__(256) void gemm1_kernel(
    const float* __restrict__ x, const short* __restrict__ W1T,
    const float* __restrict__ b1, const int* __restrict__ cnt,
    const int* __restrict__ offsets, const int* __restrict__ tok_list,
    short* __restrict__ H)
{
    int e  = blockIdx.y >> 6;
    int tm = blockIdx.y & 63;
    int ce = cnt[e];
    if (tm * 64 >= ce) return;
    int n0 = blockIdx.x * 64;

    __shared__ __align__(16) short As[64][40];
    __shared__ __align__(16) short Bs[64][40];

    int tid = threadIdx.x;
    int lane = tid & 63, wid = tid >> 6;
    int wr = wid >> 1, wc = wid & 1;
    int lrow = lane & 15, kgr = lane >> 4;

    int sr = tid >> 2, skc = (tid & 3) * 8;
    int am = tm * 64 + sr;
    bool avalid = am < ce;
    int tok = avalid ? tok_list[e * CAP + am] : 0;
    const float* asrc = x + (size_t)tok * D_MODEL + skc;
    const short* bsrc = W1T + ((size_t)e * D_FF + n0 + sr) * D_MODEL + skc;

    f32x4 acc[2][2] = {};
    for (int kt = 0; kt < D_MODEL; kt += 32) {
        s16x8 av = {};
        if (avalid) {
            f32x4 x0 = *(const f32x4*)(asrc + kt);
            f32x4 x1 = *(const f32x4*)(asrc + kt + 4);
            av = cvt8(x0, x1);
        }
        *(s16x8*)&As[sr][skc] = av;
        *(s16x8*)&Bs[sr][skc] = *(const s16x8*)(bsrc + kt);
        __syncthreads();

        s16x8 a0 = *(const s16x8*)&As[wr * 32 + lrow][kgr * 8];
        s16x8 a1 = *(const s16x8*)&As[wr * 32 + 16 + lrow][kgr * 8];
        s16x8 b0 = *(const s16x8*)&Bs[wc * 32 + lrow][kgr * 8];
        s16x8 b1v = *(const s16x8*)&Bs[wc * 32 + 16 + lrow][kgr * 8];
        acc[0][0] = __builtin_amdgcn_mfma_f32_16x16x32_bf16(a0, b0,  acc[0][0], 0, 0, 0);
        acc[0][1] = __builtin_amdgcn_mfma_f32_16x16x32_bf16(a0, b1v, acc[0][1], 0, 0, 0);
        acc[1][0] = __builtin_amdgcn_mfma_f32_16x16x32_bf16(a1, b0,  acc[1][0], 0, 0, 0);
        acc[1][1] = __builtin_amdgcn_mfma_f32_16x16x32_bf16(a1, b1v, acc[1][1], 0, 0, 0);
        __syncthreads();
    }

    int offe = offsets[e];
#pragma unroll
    for (int fm = 0; fm < 2; fm++)
#pragma unroll
    for (int fn = 0; fn < 2; fn++)
#pragma unroll
    for (int j = 0; j < 4; j++) {
        int m = tm * 64 + wr * 32 + fm * 16 + kgr * 4 + j;
        if (m >= ce) continue;
        int n = n0 + wc * 32 + fn * 16 + lrow;
        float v = acc[fm][fn][j] + b1[e * D_FF + n];
        v = 0.5f * v * (1.f + erff(v * 0.70710678118654752f));  // exact gelu
        H[(size_t)(offe + m) * D_FF + n] = f2bf(v);
    }
}

// ---------------- GEMM2: y = H[slot] @ W2[e] + b2[e]; out[tok] += wt*y (atomic) ----------------
__global__ __launch_bounds__(256) void gemm2_kernel(
    const short* __restrict__ H, const short* __restrict__ W2T,
    const float* __restrict__ b2, const int* __restrict__ cnt,
    const int* __restrict__ offsets, const int* __restrict__ tok_list,
    const float* __restrict__ wt_list, float* __restrict__ out)
{
    int e  = blockIdx.y >> 6;
    int tm = blockIdx.y & 63;
    int ce = cnt[e];
    if (tm * 64 >= ce) return;
    int offe = offsets[e];
    int n0 = blockIdx.x * 64;

    __shared__ __align__(16) short As[64][40];
    __shared__ __align__(16) short Bs[64][40];

    int tid = threadIdx.x;
    int lane = tid & 63, wid = tid >> 6;
    int wr = wid >> 1, wc = wid & 1;
    int lrow = lane & 15, kgr = lane >> 4;

    int sr = tid >> 2, skc = (tid & 3) * 8;
    int am = tm * 64 + sr;
    bool avalid = am < ce;
    const short* asrc = H + (size_t)(offe + (avalid ? am : 0)) * D_FF + skc;
    const short* bsrc = W2T + ((size_t)e * D_MODEL + n0 + sr) * D_FF + skc;

    f32x4 acc[2][2] = {};
    for (int kt = 0; kt < D_FF; kt += 32) {
        s16x8 av = {};
        if (avalid) av = *(const s16x8*)(asrc + kt);
        *(s16x8*)&As[sr][skc] = av;
        *(s16x8*)&Bs[sr][skc] = *(const s16x8*)(bsrc + kt);
        __syncthreads();

        s16x8 a0 = *(const s16x8*)&As[wr * 32 + lrow][kgr * 8];
        s16x8 a1 = *(const s16x8*)&As[wr * 32 + 16 + lrow][kgr * 8];
        s16x8 b0 = *(const s16x8*)&Bs[wc * 32 + lrow][kgr * 8];
        s16x8 b1v = *(const s16x8*)&Bs[wc * 32 + 16 + lrow][kgr * 8];
        acc[0][0] = __builtin_amdgcn_mfma_f32_16x16x32_bf16(a0, b0,  acc[0][0], 0, 0, 0);
        acc[0][1] = __builtin_amdgcn_mfma_f32_16x16x32_bf16(a0, b1v, acc[0][1], 0, 0, 0);
        acc[1][0] = __builtin_amdgcn_mfma_f32_16x16x32_bf16(a1, b0,  acc[1][0], 0, 0, 0);
        acc[1][1] = __builtin_amdgcn_mfma_f32_16x16x32_bf16(a1, b1v, acc[1][1], 0, 0, 0);
        __syncthreads();
    }

#pragma unroll
    for (int fm = 0; fm < 2; fm++)
#pragma unroll
    for (int fn = 0; fn < 2; fn++)
#pragma unroll
    for (int j = 0; j < 4; j++) {
        int m = tm * 64 + wr * 32 + fm * 16 + kgr * 4 + j;
        if (m >= ce) continue;
        int n = n0 + wc * 32 + fn * 16 + lrow;
        int tok = tok_list[e * CAP + m];
        float wt = wt_list[e * CAP + m];
        float v = acc[fm][fn][j] + b2[e * D_MODEL + n];
        atomicAdd(&out[(size_t)tok * D_MODEL + n], wt * v);
    }
}

extern "C" void kernel_launch(void* const* d_in, const int* in_sizes, int n_in,
                              void* d_out, int out_size, void* d_ws, size_t ws_size,
                              hipStream_t stream)
{
    const float* x  = (const float*)d_in[0];
    const float* gw = (const float*)d_in[1];
    const float* gb = (const float*)d_in[2];
    const float* w1 = (const float*)d_in[3];
    const float* b1 = (const float*)d_in[4];
    const float* w2 = (const float*)d_in[5];
    const float* b2 = (const float*)d_in[6];
    float* out = (float*)d_out;

    // workspace layout (needs ~134.5 MB)
    char* w = (char*)d_ws;
    int*   cnt      = (int*)(w + 0);
    float* usage    = (float*)(w + 32);
    int*   offsets  = (int*)(w + 64);
    int*   tok_list = (int*)(w + 128);
    float* wt_list  = (float*)(w + 128 + NE * CAP * 4);
    short* WT       = (short*)(w + 128 + 2 * NE * CAP * 4);                 // 8*4096*1024 bf16, reused for W1T then W2T
    short* H        = (short*)(w + 128 + 2 * NE * CAP * 4 + (size_t)NE * D_FF * D_MODEL * 2);

    hipMemsetAsync(d_ws, 0, 128, stream);                                   // cnt, usage, offsets
    hipMemsetAsync(d_out, 0, (size_t)out_size * sizeof(float), stream);     // out accumulated atomically

    router_kernel<<<NTOK, 64, 0, stream>>>(x, gw, gb, cnt, usage, tok_list, wt_list);
    finalize_router<<<1, 1, 0, stream>>>(cnt, usage, offsets, out + (size_t)NTOK * D_MODEL);

    // W1 [1024][4096] -> W1T [4096][1024] bf16
    transpose_cvt<<<dim3(D_FF / 32, D_MODEL / 32, NE), dim3(32, 8), 0, stream>>>(w1, WT, D_MODEL, D_FF);
    gemm1_kernel<<<dim3(D_FF / 64, NE * (CAP / 64)), 256, 0, stream>>>(
        x, WT, b1, cnt, offsets, tok_list, H);

    // W2 [4096][1024] -> W2T [1024][4096] bf16 (reuse WT buffer; stream-ordered after gemm1)
    transpose_cvt<<<dim3(D_MODEL / 32, D_FF / 32, NE), dim3(32, 8), 0, stream>>>(w2, WT, D_FF, D_MODEL);
    gemm2_kernel<<<dim3(D_MODEL / 64, NE * (CAP / 64)), 256, 0, stream>>>(
        H, WT, b2, cnt, offsets, tok_list, wt_list, out);
}

// Round 2
// 519.731 us; speedup vs baseline: 1.9372x; 1.9372x over previous
//
#include <hip/hip_runtime.h>
#include <hip/hip_bf16.h>
#include <math.h>

// MoE top-2 of 8 experts. D_MODEL=1024, D_FF=4096, tokens = 2*2048 = 4096.
// R1: router rewritten to eliminate per-token global atomics (was 520us of
// atomic serialization on usage[]/cnt[]). Per-block LDS aggregation + separate
// per-expert list compaction kernel.

#define D_MODEL 1024
#define D_FF    4096
#define NE      8
#define NTOK    4096
#define CAP     4096   // per-expert capacity (max possible = NTOK)

typedef __attribute__((ext_vector_type(4))) float f32x4;
typedef __attribute__((ext_vector_type(8))) short s16x8;

__device__ __forceinline__ short f2bf(float f) {
    union { float f; unsigned u; } v; v.f = f;
    unsigned r = v.u + 0x7FFFu + ((v.u >> 16) & 1u);  // RNE
    return (short)(r >> 16);
}

__device__ __forceinline__ s16x8 cvt8(f32x4 a, f32x4 b) {
    s16x8 r;
    r[0]=f2bf(a[0]); r[1]=f2bf(a[1]); r[2]=f2bf(a[2]); r[3]=f2bf(a[3]);
    r[4]=f2bf(b[0]); r[5]=f2bf(b[1]); r[6]=f2bf(b[2]); r[7]=f2bf(b[3]);
    return r;
}

// ---------------- Router: wave per token, grid-stride; no per-token global atomics ----
__global__ __launch_bounds__(256) void router_kernel(
    const float* __restrict__ x, const float* __restrict__ gw,
    const float* __restrict__ gb,
    float* __restrict__ usage, int* __restrict__ eidx, float* __restrict__ wgt)
{
    __shared__ float s_gw[NE][D_MODEL];   // 32 KB
    __shared__ float s_usage[NE];
    int tid = threadIdx.x;
    for (int i = tid * 4; i < NE * D_MODEL; i += 256 * 4)
        *(f32x4*)&s_gw[0][i] = *(const f32x4*)(gw + i);
    if (tid < NE) s_usage[tid] = 0.f;
    __syncthreads();

    int wid = tid >> 6, lane = tid & 63;
    int wave_stride = gridDim.x * 4;
    float l_usage[NE];
#pragma unroll
    for (int e = 0; e < NE; e++) l_usage[e] = 0.f;

    for (int t = blockIdx.x * 4 + wid; t < NTOK; t += wave_stride) {
        const float* xr = x + (size_t)t * D_MODEL;
        float acc[NE];
#pragma unroll
        for (int e = 0; e < NE; e++) acc[e] = 0.f;
        for (int i = lane * 4; i < D_MODEL; i += 64 * 4) {
            f32x4 xv = *(const f32x4*)(xr + i);
#pragma unroll
            for (int e = 0; e < NE; e++) {
                f32x4 gv = *(const f32x4*)&s_gw[e][i];
                acc[e] += xv[0]*gv[0] + xv[1]*gv[1] + xv[2]*gv[2] + xv[3]*gv[3];
            }
        }
#pragma unroll
        for (int e = 0; e < NE; e++) {
            float a = acc[e];
            for (int off = 32; off; off >>= 1) a += __shfl_down(a, off);
            acc[e] = a;
        }
        if (lane == 0) {
            float logits[NE];
            float mx = -1e30f;
#pragma unroll
            for (int e = 0; e < NE; e++) { logits[e] = acc[e] + gb[e]; mx = fmaxf(mx, logits[e]); }
            float se = 0.f;
            float pe[NE];
#pragma unroll
            for (int e = 0; e < NE; e++) { pe[e] = expf(logits[e] - mx); se += pe[e]; }
            float inv = 1.f / se;
#pragma unroll
            for (int e = 0; e < NE; e++) l_usage[e] += pe[e] * inv;
            // top-2 (ties -> lower index, matches lax.top_k)
            int i0 = 0;
#pragma unroll
            for (int e = 1; e < NE; e++) if (logits[e] > logits[i0]) i0 = e;
            int i1 = -1;
#pragma unroll
            for (int e = 0; e < NE; e++) {
                if (e == i0) continue;
                if (i1 < 0 || logits[e] > logits[i1]) i1 = e;
            }
            float w0 = 1.f / (1.f + expf(logits[i1] - logits[i0]));
            eidx[t] = i0 | (i1 << 8);
            wgt[t] = w0;
        }
    }
    if (lane == 0) {
#pragma unroll
        for (int e = 0; e < NE; e++) atomicAdd(&s_usage[e], l_usage[e]);  // LDS atomic
    }
    __syncthreads();
    if (tid < NE) atomicAdd(&usage[tid], s_usage[tid]);  // 8 global atomics / block
}

// ---------------- per-expert list compaction (LDS atomics only) ----------------
__global__ __launch_bounds__(256) void build_lists(
    const int* __restrict__ eidx, const float* __restrict__ wgt,
    int* __restrict__ cnt, int* __restrict__ tok_list, float* __restrict__ wt_list)
{
    int e = blockIdx.x;
    __shared__ int s_cnt;
    if (threadIdx.x == 0) s_cnt = 0;
    __syncthreads();
    for (int t = threadIdx.x; t < NTOK; t += 256) {
        int p = eidx[t];
        float w0 = wgt[t];
        if ((p & 255) == e) {
            int s = atomicAdd(&s_cnt, 1);
            tok_list[e * CAP + s] = t; wt_list[e * CAP + s] = w0;
        }
        if ((p >> 8) == e) {
            int s = atomicAdd(&s_cnt, 1);
            tok_list[e * CAP + s] = t; wt_list[e * CAP + s] = 1.f - w0;
        }
    }
    __syncthreads();
    if (threadIdx.x == 0) cnt[e] = s_cnt;
}

// ---------------- prefix offsets + load-balancing loss ----------------
__global__ void finalize_router(const int* __restrict__ cnt,
                                const float* __restrict__ usage,
                                int* __restrict__ offsets,
                                float* __restrict__ out_loss)
{
    int o = 0;
    for (int e = 0; e < NE; e++) { offsets[e] = o; o += cnt[e]; }
    float s = 0.f;
    for (int e = 0; e < NE; e++) { float u = usage[e] / (float)NTOK; s += u * u; }
    *out_loss = (float)NE * s - 1.f;
}

// ---------------- transpose + fp32->bf16: src[R][C] -> dst[C][R], per expert z ----------------
__global__ __launch_bounds__(256) void transpose_cvt(
    const float* __restrict__ src, short* __restrict__ dst, int R, int C)
{
    __shared__ float tile[32][33];
    int e = blockIdx.z;
    src += (size_t)e * R * C;
    dst += (size_t)e * R * C;
    int c0 = blockIdx.x * 32, r0 = blockIdx.y * 32;
    int tx = threadIdx.x, ty = threadIdx.y;   // 32 x 8
#pragma unroll
    for (int j = 0; j < 4; j++)
        tile[ty * 4 + j][tx] = src[(size_t)(r0 + ty * 4 + j) * C + c0 + tx];
    __syncthreads();
#pragma unroll
    for (int j = 0; j < 4; j++)
        dst[(size_t)(c0 + ty * 4 + j) * R + r0 + tx] = f2bf(tile[tx][ty * 4 + j]);
}

// ---------------- GEMM1: H[slot][f] = gelu( x[tok] @ W1[e] + b1[e] ), bf16 out ----------------
__global__ __launch_bounds__(256) void gemm1_kernel(
    const float* __restrict__ x, const short* __restrict__ W1T,
    const float* __restrict__ b1, const int* __restrict__ cnt,
    const int* __restrict__ offsets, const int* __restrict__ tok_list,
    short* __restrict__ H)
{
    int e  = blockIdx.y >> 6;
    int tm = blockIdx.y & 63;
    int ce = cnt[e];
    if (tm * 64 >= ce) return;
    int n0 = blockIdx.x * 64;

    __shared__ __align__(16) short As[64][40];
    __shared__ __align__(16) short Bs[64][40];

    int tid = threadIdx.x;
    int lane = tid & 63, wid = tid >> 6;
    int wr = wid >> 1, wc = wid & 1;
    int lrow = lane & 15, kgr = lane >> 4;

    int sr = tid >> 2, skc = (tid & 3) * 8;
    int am = tm * 64 + sr;
    bool avalid = am < ce;
    int tok = avalid ? tok_list[e * CAP + am] : 0;
    const float* asrc = x + (size_t)tok * D_MODEL + skc;
    const short* bsrc = W1T + ((size_t)e * D_FF + n0 + sr) * D_MODEL + skc;

    f32x4 acc[2][2] = {};
    for (int kt = 0; kt < D_MODEL; kt += 32) {
        s16x8 av = {};
        if (avalid) {
            f32x4 x0 = *(const f32x4*)(asrc + kt);
            f32x4 x1 = *(const f32x4*)(asrc + kt + 4);
            av = cvt8(x0, x1);
        }
        *(s16x8*)&As[sr][skc] = av;
        *(s16x8*)&Bs[sr][skc] = *(const s16x8*)(bsrc + kt);
        __syncthreads();

        s16x8 a0 = *(const s16x8*)&As[wr * 32 + lrow][kgr * 8];
        s16x8 a1 = *(const s16x8*)&As[wr * 32 + 16 + lrow][kgr * 8];
        s16x8 b0 = *(const s16x8*)&Bs[wc * 32 + lrow][kgr * 8];
        s16x8 b1v = *(const s16x8*)&Bs[wc * 32 + 16 + lrow][kgr * 8];
        acc[0][0] = __builtin_amdgcn_mfma_f32_16x16x32_bf16(a0, b0,  acc[0][0], 0, 0, 0);
        acc[0][1] = __builtin_amdgcn_mfma_f32_16x16x32_bf16(a0, b1v, acc[0][1], 0, 0, 0);
        acc[1][0] = __builtin_amdgcn_mfma_f32_16x16x32_bf16(a1, b0,  acc[1][0], 0, 0, 0);
        acc[1][1] = __builtin_amdgcn_mfma_f32_16x16x32_bf16(a1, b1v, acc[1][1], 0, 0, 0);
        __syncthreads();
    }

    int offe = offsets[e];
#pragma unroll
    for (int fm = 0; fm < 2; fm++)
#pragma unroll
    for (int fn = 0; fn < 2; fn++)
#pragma unroll
    for (int j = 0; j < 4; j++) {
        int m = tm * 64 + wr * 32 + fm * 16 + kgr * 4 + j;
        if (m >= ce) continue;
        int n = n0 + wc * 32 + fn * 16 + lrow;
        float v = acc[fm][fn][j] + b1[e * D_FF + n];
        v = 0.5f * v * (1.f + erff(v * 0.70710678118654752f));  // exact gelu
        H[(size_t)(offe + m) * D_FF + n] = f2bf(v);
    }
}

// ---------------- GEMM2: y = H[slot] @ W2[e] + b2[e]; out[tok] += wt*y (atomic) ----------------
__global__ __launch_bounds__(256) void gemm2_kernel(
    const short* __restrict__ H, const short* __restrict__ W2T,
    const float* __restrict__ b2, const int* __restrict__ cnt,
    const int* __restrict__ offsets, const int* __restrict__ tok_list,
    const float* __restrict__ wt_list, float* __restrict__ out)
{
    int e  = blockIdx.y >> 6;
    int tm = blockIdx.y & 63;
    int ce = cnt[e];
    if (tm * 64 >= ce) return;
    int offe = offsets[e];
    int n0 = blockIdx.x * 64;

    __shared__ __align__(16) short As[64][40];
    __shared__ __align__(16) short Bs[64][40];

    int tid = threadIdx.x;
    int lane = tid & 63, wid = tid >> 6;
    int wr = wid >> 1, wc = wid & 1;
    int lrow = lane & 15, kgr = lane >> 4;

    int sr = tid >> 2, skc = (tid & 3) * 8;
    int am = tm * 64 + sr;
    bool avalid = am < ce;
    const short* asrc = H + (size_t)(offe + (avalid ? am : 0)) * D_FF + skc;
    const short* bsrc = W2T + ((size_t)e * D_MODEL + n0 + sr) * D_FF + skc;

    f32x4 acc[2][2] = {};
    for (int kt = 0; kt < D_FF; kt += 32) {
        s16x8 av = {};
        if (avalid) av = *(const s16x8*)(asrc + kt);
        *(s16x8*)&As[sr][skc] = av;
        *(s16x8*)&Bs[sr][skc] = *(const s16x8*)(bsrc + kt);
        __syncthreads();

        s16x8 a0 = *(const s16x8*)&As[wr * 32 + lrow][kgr * 8];
        s16x8 a1 = *(const s16x8*)&As[wr * 32 + 16 + lrow][kgr * 8];
        s16x8 b0 = *(const s16x8*)&Bs[wc * 32 + lrow][kgr * 8];
        s16x8 b1v = *(const s16x8*)&Bs[wc * 32 + 16 + lrow][kgr * 8];
        acc[0][0] = __builtin_amdgcn_mfma_f32_16x16x32_bf16(a0, b0,  acc[0][0], 0, 0, 0);
        acc[0][1] = __builtin_amdgcn_mfma_f32_16x16x32_bf16(a0, b1v, acc[0][1], 0, 0, 0);
        acc[1][0] = __builtin_amdgcn_mfma_f32_16x16x32_bf16(a1, b0,  acc[1][0], 0, 0, 0);
        acc[1][1] = __builtin_amdgcn_mfma_f32_16x16x32_bf16(a1, b1v, acc[1][1], 0, 0, 0);
        __syncthreads();
    }

#pragma unroll
    for (int fm = 0; fm < 2; fm++)
#pragma unroll
    for (int fn = 0; fn < 2; fn++)
#pragma unroll
    for (int j = 0; j < 4; j++) {
        int m = tm * 64 + wr * 32 + fm * 16 + kgr * 4 + j;
        if (m >= ce) continue;
        int n = n0 + wc * 32 + fn * 16 + lrow;
        int tok = tok_list[e * CAP + m];
        float wt = wt_list[e * CAP + m];
        float v = acc[fm][fn][j] + b2[e * D_MODEL + n];
        atomicAdd(&out[(size_t)tok * D_MODEL + n], wt * v);
    }
}

extern "C" void kernel_launch(void* const* d_in, const int* in_sizes, int n_in,
                              void* d_out, int out_size, void* d_ws, size_t ws_size,
                              hipStream_t stream)
{
    const float* x  = (const float*)d_in[0];
    const float* gw = (const float*)d_in[1];
    const float* gb = (const float*)d_in[2];
    const float* w1 = (const float*)d_in[3];
    const float* b1 = (const float*)d_in[4];
    const float* w2 = (const float*)d_in[5];
    const float* b2 = (const float*)d_in[6];
    float* out = (float*)d_out;

    // workspace layout (~134.5 MB)
    char* w = (char*)d_ws;
    int*   cnt      = (int*)(w + 0);
    float* usage    = (float*)(w + 32);
    int*   offsets  = (int*)(w + 64);
    int*   tok_list = (int*)(w + 128);
    float* wt_list  = (float*)(w + 128 + NE * CAP * 4);
    short* WT       = (short*)(w + 128 + 2 * NE * CAP * 4);  // 8*4096*1024 bf16; W1T then W2T
    short* H        = (short*)(w + 128 + 2 * NE * CAP * 4 + (size_t)NE * D_FF * D_MODEL * 2);
    // eidx/wgt alias the start of WT (consumed by build_lists BEFORE transpose_cvt writes WT)
    int*   eidx     = (int*)WT;
    float* wgt      = (float*)(WT + NTOK * 2);

    hipMemsetAsync(d_ws, 0, 128, stream);                                // cnt, usage, offsets
    hipMemsetAsync(d_out, 0, (size_t)out_size * sizeof(float), stream);  // atomic-accumulated

    router_kernel<<<256, 256, 0, stream>>>(x, gw, gb, usage, eidx, wgt);
    build_lists<<<NE, 256, 0, stream>>>(eidx, wgt, cnt, tok_list, wt_list);
    finalize_router<<<1, 1, 0, stream>>>(cnt, usage, offsets, out + (size_t)NTOK * D_MODEL);

    // W1 [1024][4096] -> W1T [4096][1024] bf16
    transpose_cvt<<<dim3(D_FF / 32, D_MODEL / 32, NE), dim3(32, 8), 0, stream>>>(w1, WT, D_MODEL, D_FF);
    gemm1_kernel<<<dim3(D_FF / 64, NE * (CAP / 64)), 256, 0, stream>>>(
        x, WT, b1, cnt, offsets, tok_list, H);

    // W2 [4096][1024] -> W2T [1024][4096] bf16 (reuse WT; stream-ordered after gemm1)
    transpose_cvt<<<dim3(D_MODEL / 32, D_FF / 32, NE), dim3(32, 8), 0, stream>>>(w2, WT, D_FF, D_MODEL);
    gemm2_kernel<<<dim3(D_MODEL / 64, NE * (CAP / 64)), 256, 0, stream>>>(
        H, WT, b2, cnt, offsets, tok_list, wt_list, out);
}

// Round 3
// 406.583 us; speedup vs baseline: 2.4763x; 1.2783x over previous
//
#include <hip/hip_runtime.h>
#include <hip/hip_bf16.h>
#include <math.h>

// MoE top-2 of 8 experts. D_MODEL=1024, D_FF=4096, tokens = 2*2048 = 4096.
// R2: GEMMs upgraded 64x64-tile -> 128x128-tile (4x4 frags/wave) with
// global_load_lds(16B) async staging (m93->m97 ladder). Router/lists unchanged.

#define D_MODEL 1024
#define D_FF    4096
#define NE      8
#define NTOK    4096
#define CAP     4096   // per-expert capacity (max possible = NTOK)

typedef __attribute__((ext_vector_type(4))) float f32x4;
typedef __attribute__((ext_vector_type(8))) short s16x8;

__device__ __forceinline__ short f2bf(float f) {
    union { float f; unsigned u; } v; v.f = f;
    unsigned r = v.u + 0x7FFFu + ((v.u >> 16) & 1u);  // RNE
    return (short)(r >> 16);
}

__device__ __forceinline__ s16x8 cvt8(f32x4 a, f32x4 b) {
    s16x8 r;
    r[0]=f2bf(a[0]); r[1]=f2bf(a[1]); r[2]=f2bf(a[2]); r[3]=f2bf(a[3]);
    r[4]=f2bf(b[0]); r[5]=f2bf(b[1]); r[6]=f2bf(b[2]); r[7]=f2bf(b[3]);
    return r;
}

// async global -> LDS, 16 bytes/lane. LDS dest must be wave-uniform base;
// HW writes base + lane*16 (m104/m108). Global src is per-lane.
__device__ __forceinline__ void gload16(const void* g, void* l) {
    __builtin_amdgcn_global_load_lds(
        (const __attribute__((address_space(1))) unsigned*)g,
        (__attribute__((address_space(3))) unsigned*)l, 16, 0, 0);
}

// ---------------- Router: wave per token, grid-stride; no per-token global atomics ----
__global__ __launch_bounds__(256) void router_kernel(
    const float* __restrict__ x, const float* __restrict__ gw,
    const float* __restrict__ gb,
    float* __restrict__ usage, int* __restrict__ eidx, float* __restrict__ wgt)
{
    __shared__ float s_gw[NE][D_MODEL];   // 32 KB
    __shared__ float s_usage[NE];
    int tid = threadIdx.x;
    for (int i = tid * 4; i < NE * D_MODEL; i += 256 * 4)
        *(f32x4*)&s_gw[0][i] = *(const f32x4*)(gw + i);
    if (tid < NE) s_usage[tid] = 0.f;
    __syncthreads();

    int wid = tid >> 6, lane = tid & 63;
    int wave_stride = gridDim.x * 4;
    float l_usage[NE];
#pragma unroll
    for (int e = 0; e < NE; e++) l_usage[e] = 0.f;

    for (int t = blockIdx.x * 4 + wid; t < NTOK; t += wave_stride) {
        const float* xr = x + (size_t)t * D_MODEL;
        float acc[NE];
#pragma unroll
        for (int e = 0; e < NE; e++) acc[e] = 0.f;
        for (int i = lane * 4; i < D_MODEL; i += 64 * 4) {
            f32x4 xv = *(const f32x4*)(xr + i);
#pragma unroll
            for (int e = 0; e < NE; e++) {
                f32x4 gv = *(const f32x4*)&s_gw[e][i];
                acc[e] += xv[0]*gv[0] + xv[1]*gv[1] + xv[2]*gv[2] + xv[3]*gv[3];
            }
        }
#pragma unroll
        for (int e = 0; e < NE; e++) {
            float a = acc[e];
            for (int off = 32; off; off >>= 1) a += __shfl_down(a, off);
            acc[e] = a;
        }
        if (lane == 0) {
            float logits[NE];
            float mx = -1e30f;
#pragma unroll
            for (int e = 0; e < NE; e++) { logits[e] = acc[e] + gb[e]; mx = fmaxf(mx, logits[e]); }
            float se = 0.f;
            float pe[NE];
#pragma unroll
            for (int e = 0; e < NE; e++) { pe[e] = expf(logits[e] - mx); se += pe[e]; }
            float inv = 1.f / se;
#pragma unroll
            for (int e = 0; e < NE; e++) l_usage[e] += pe[e] * inv;
            int i0 = 0;
#pragma unroll
            for (int e = 1; e < NE; e++) if (logits[e] > logits[i0]) i0 = e;
            int i1 = -1;
#pragma unroll
            for (int e = 0; e < NE; e++) {
                if (e == i0) continue;
                if (i1 < 0 || logits[e] > logits[i1]) i1 = e;
            }
            float w0 = 1.f / (1.f + expf(logits[i1] - logits[i0]));
            eidx[t] = i0 | (i1 << 8);
            wgt[t] = w0;
        }
    }
    if (lane == 0) {
#pragma unroll
        for (int e = 0; e < NE; e++) atomicAdd(&s_usage[e], l_usage[e]);  // LDS atomic
    }
    __syncthreads();
    if (tid < NE) atomicAdd(&usage[tid], s_usage[tid]);  // 8 global atomics / block
}

// ---------------- per-expert list compaction (LDS atomics only) ----------------
__global__ __launch_bounds__(256) void build_lists(
    const int* __restrict__ eidx, const float* __restrict__ wgt,
    int* __restrict__ cnt, int* __restrict__ tok_list, float* __restrict__ wt_list)
{
    int e = blockIdx.x;
    __shared__ int s_cnt;
    if (threadIdx.x == 0) s_cnt = 0;
    __syncthreads();
    for (int t = threadIdx.x; t < NTOK; t += 256) {
        int p = eidx[t];
        float w0 = wgt[t];
        if ((p & 255) == e) {
            int s = atomicAdd(&s_cnt, 1);
            tok_list[e * CAP + s] = t; wt_list[e * CAP + s] = w0;
        }
        if ((p >> 8) == e) {
            int s = atomicAdd(&s_cnt, 1);
            tok_list[e * CAP + s] = t; wt_list[e * CAP + s] = 1.f - w0;
        }
    }
    __syncthreads();
    if (threadIdx.x == 0) cnt[e] = s_cnt;
}

// ---------------- prefix offsets + load-balancing loss ----------------
__global__ void finalize_router(const int* __restrict__ cnt,
                                const float* __restrict__ usage,
                                int* __restrict__ offsets,
                                float* __restrict__ out_loss)
{
    int o = 0;
    for (int e = 0; e < NE; e++) { offsets[e] = o; o += cnt[e]; }
    float s = 0.f;
    for (int e = 0; e < NE; e++) { float u = usage[e] / (float)NTOK; s += u * u; }
    *out_loss = (float)NE * s - 1.f;
}

// ---------------- transpose + fp32->bf16: src[R][C] -> dst[C][R], per expert z ----------------
__global__ __launch_bounds__(256) void transpose_cvt(
    const float* __restrict__ src, short* __restrict__ dst, int R, int C)
{
    __shared__ float tile[32][33];
    int e = blockIdx.z;
    src += (size_t)e * R * C;
    dst += (size_t)e * R * C;
    int c0 = blockIdx.x * 32, r0 = blockIdx.y * 32;
    int tx = threadIdx.x, ty = threadIdx.y;   // 32 x 8
#pragma unroll
    for (int j = 0; j < 4; j++)
        tile[ty * 4 + j][tx] = src[(size_t)(r0 + ty * 4 + j) * C + c0 + tx];
    __syncthreads();
#pragma unroll
    for (int j = 0; j < 4; j++)
        dst[(size_t)(c0 + ty * 4 + j) * R + r0 + tx] = f2bf(tile[tx][ty * 4 + j]);
}

// ---------------- GEMM1: H[slot][f] = gelu( x[tok] @ W1[e] + b1[e] ), bf16 out ----
// 128x128 tile, BK=32, 4 waves (2x2), 4x4 16x16x32 frags/wave.
// B via global_load_lds(16); A reg-staged fp32->bf16 (needs cvt).
__global__ __launch_bounds__(256) void gemm1_kernel(
    const float* __restrict__ x, const short* __restrict__ W1T,
    const float* __restrict__ b1, const int* __restrict__ cnt,
    const int* __restrict__ offsets, const int* __restrict__ tok_list,
    short* __restrict__ H)
{
    int e  = blockIdx.y >> 5;
    int tm = blockIdx.y & 31;
    int ce = cnt[e];
    if (tm * 128 >= ce) return;
    int n0 = blockIdx.x * 128;

    __shared__ __align__(16) short As[128][32];
    __shared__ __align__(16) short Bs[128][32];

    int tid = threadIdx.x;
    int lane = tid & 63, wid = tid >> 6;
    int wr = wid >> 1, wc = wid & 1;
    int lrow = lane & 15, kgr = lane >> 4;

    // B staging: issue i covers rows i*64 + wid*16 + (lane>>2), 8 bf16 at col (lane&3)*8
    int srow = wid * 16 + (lane >> 2);
    int scol = (lane & 3) * 8;
    const short* bsrc0 = W1T + ((size_t)e * D_FF + n0 + srow) * D_MODEL + scol;
    const short* bsrc1 = bsrc0 + (size_t)64 * D_MODEL;

    // A staging: thread owns row ar = tid>>1, 16 cols at ac
    int ar = tid >> 1, ac = (tid & 1) * 16;
    int am = tm * 128 + ar;
    int tok = tok_list[e * CAP + (am < ce ? am : 0)];
    const float* asrc = x + (size_t)tok * D_MODEL + ac;

    f32x4 acc[4][4] = {};
    for (int kt = 0; kt < D_MODEL; kt += 32) {
        gload16(bsrc0 + kt, &Bs[wid * 16][0]);
        gload16(bsrc1 + kt, &Bs[64 + wid * 16][0]);
        f32x4 x0 = *(const f32x4*)(asrc + kt);
        f32x4 x1 = *(const f32x4*)(asrc + kt + 4);
        f32x4 x2 = *(const f32x4*)(asrc + kt + 8);
        f32x4 x3 = *(const f32x4*)(asrc + kt + 12);
        *(s16x8*)&As[ar][ac]     = cvt8(x0, x1);
        *(s16x8*)&As[ar][ac + 8] = cvt8(x2, x3);
        __syncthreads();

        s16x8 a[4], b[4];
#pragma unroll
        for (int i = 0; i < 4; i++) {
            a[i] = *(const s16x8*)&As[wr * 64 + i * 16 + lrow][kgr * 8];
            b[i] = *(const s16x8*)&Bs[wc * 64 + i * 16 + lrow][kgr * 8];
        }
#pragma unroll
        for (int i = 0; i < 4; i++)
#pragma unroll
        for (int j = 0; j < 4; j++)
            acc[i][j] = __builtin_amdgcn_mfma_f32_16x16x32_bf16(a[i], b[j], acc[i][j], 0, 0, 0);
        __syncthreads();
    }

    int offe = offsets[e];
    float bn[4];
#pragma unroll
    for (int j = 0; j < 4; j++) bn[j] = b1[e * D_FF + n0 + wc * 64 + j * 16 + lrow];
#pragma unroll
    for (int i = 0; i < 4; i++) {
#pragma unroll
        for (int q = 0; q < 4; q++) {
            int m = tm * 128 + wr * 64 + i * 16 + kgr * 4 + q;
            if (m >= ce) continue;
            short* hrow = H + (size_t)(offe + m) * D_FF;
#pragma unroll
            for (int j = 0; j < 4; j++) {
                int n = n0 + wc * 64 + j * 16 + lrow;
                float v = acc[i][j][q] + bn[j];
                v = 0.5f * v * (1.f + erff(v * 0.70710678118654752f));  // exact gelu
                hrow[n] = f2bf(v);
            }
        }
    }
}

// ---------------- GEMM2: y = H[slot] @ W2[e] + b2[e]; out[tok] += wt*y (atomic) ----
// 128x128 tile, BK=32; both A (H) and B (W2T) via global_load_lds(16).
__global__ __launch_bounds__(256) void gemm2_kernel(
    const short* __restrict__ H, const short* __restrict__ W2T,
    const float* __restrict__ b2, const int* __restrict__ cnt,
    const int* __restrict__ offsets, const int* __restrict__ tok_list,
    const float* __restrict__ wt_list, float* __restrict__ out)
{
    int e  = blockIdx.y >> 5;
    int tm = blockIdx.y & 31;
    int ce = cnt[e];
    if (tm * 128 >= ce) return;
    int offe = offsets[e];
    int n0 = blockIdx.x * 128;

    __shared__ __align__(16) short As[128][32];
    __shared__ __align__(16) short Bs[128][32];

    int tid = threadIdx.x;
    int lane = tid & 63, wid = tid >> 6;
    int wr = wid >> 1, wc = wid & 1;
    int lrow = lane & 15, kgr = lane >> 4;

    int srow = wid * 16 + (lane >> 2);
    int scol = (lane & 3) * 8;
    int am0 = tm * 128 + srow, am1 = am0 + 64;
    const short* asrc0 = H + (size_t)(offe + (am0 < ce ? am0 : 0)) * D_FF + scol;
    const short* asrc1 = H + (size_t)(offe + (am1 < ce ? am1 : 0)) * D_FF + scol;
    const short* bsrc0 = W2T + ((size_t)e * D_MODEL + n0 + srow) * D_FF + scol;
    const short* bsrc1 = bsrc0 + (size_t)64 * D_FF;

    f32x4 acc[4][4] = {};
    for (int kt = 0; kt < D_FF; kt += 32) {
        gload16(asrc0 + kt, &As[wid * 16][0]);
        gload16(asrc1 + kt, &As[64 + wid * 16][0]);
        gload16(bsrc0 + kt, &Bs[wid * 16][0]);
        gload16(bsrc1 + kt, &Bs[64 + wid * 16][0]);
        __syncthreads();

        s16x8 a[4], b[4];
#pragma unroll
        for (int i = 0; i < 4; i++) {
            a[i] = *(const s16x8*)&As[wr * 64 + i * 16 + lrow][kgr * 8];
            b[i] = *(const s16x8*)&Bs[wc * 64 + i * 16 + lrow][kgr * 8];
        }
#pragma unroll
        for (int i = 0; i < 4; i++)
#pragma unroll
        for (int j = 0; j < 4; j++)
            acc[i][j] = __builtin_amdgcn_mfma_f32_16x16x32_bf16(a[i], b[j], acc[i][j], 0, 0, 0);
        __syncthreads();
    }

    float bn[4];
#pragma unroll
    for (int j = 0; j < 4; j++) bn[j] = b2[e * D_MODEL + n0 + wc * 64 + j * 16 + lrow];
#pragma unroll
    for (int i = 0; i < 4; i++) {
#pragma unroll
        for (int q = 0; q < 4; q++) {
            int m = tm * 128 + wr * 64 + i * 16 + kgr * 4 + q;
            if (m >= ce) continue;
            int tokm = tok_list[e * CAP + m];
            float wt = wt_list[e * CAP + m];
            float* orow = out + (size_t)tokm * D_MODEL;
#pragma unroll
            for (int j = 0; j < 4; j++) {
                int n = n0 + wc * 64 + j * 16 + lrow;
                atomicAdd(&orow[n], wt * (acc[i][j][q] + bn[j]));
            }
        }
    }
}

extern "C" void kernel_launch(void* const* d_in, const int* in_sizes, int n_in,
                              void* d_out, int out_size, void* d_ws, size_t ws_size,
                              hipStream_t stream)
{
    const float* x  = (const float*)d_in[0];
    const float* gw = (const float*)d_in[1];
    const float* gb = (const float*)d_in[2];
    const float* w1 = (const float*)d_in[3];
    const float* b1 = (const float*)d_in[4];
    const float* w2 = (const float*)d_in[5];
    const float* b2 = (const float*)d_in[6];
    float* out = (float*)d_out;

    // workspace layout (~134.5 MB)
    char* w = (char*)d_ws;
    int*   cnt      = (int*)(w + 0);
    float* usage    = (float*)(w + 32);
    int*   offsets  = (int*)(w + 64);
    int*   tok_list = (int*)(w + 128);
    float* wt_list  = (float*)(w + 128 + NE * CAP * 4);
    short* WT       = (short*)(w + 128 + 2 * NE * CAP * 4);  // 8*4096*1024 bf16; W1T then W2T
    short* H        = (short*)(w + 128 + 2 * NE * CAP * 4 + (size_t)NE * D_FF * D_MODEL * 2);
    // eidx/wgt alias the start of WT (consumed by build_lists BEFORE transpose_cvt writes WT)
    int*   eidx     = (int*)WT;
    float* wgt      = (float*)(WT + NTOK * 2);

    hipMemsetAsync(d_ws, 0, 128, stream);                                // cnt, usage, offsets
    hipMemsetAsync(d_out, 0, (size_t)out_size * sizeof(float), stream);  // atomic-accumulated

    router_kernel<<<256, 256, 0, stream>>>(x, gw, gb, usage, eidx, wgt);
    build_lists<<<NE, 256, 0, stream>>>(eidx, wgt, cnt, tok_list, wt_list);
    finalize_router<<<1, 1, 0, stream>>>(cnt, usage, offsets, out + (size_t)NTOK * D_MODEL);

    // W1 [1024][4096] -> W1T [4096][1024] bf16
    transpose_cvt<<<dim3(D_FF / 32, D_MODEL / 32, NE), dim3(32, 8), 0, stream>>>(w1, WT, D_MODEL, D_FF);
    gemm1_kernel<<<dim3(D_FF / 128, NE * (CAP / 128)), 256, 0, stream>>>(
        x, WT, b1, cnt, offsets, tok_list, H);

    // W2 [4096][1024] -> W2T [1024][4096] bf16 (reuse WT; stream-ordered after gemm1)
    transpose_cvt<<<dim3(D_MODEL / 32, D_FF / 32, NE), dim3(32, 8), 0, stream>>>(w2, WT, D_FF, D_MODEL);
    gemm2_kernel<<<dim3(D_MODEL / 128, NE * (CAP / 128)), 256, 0, stream>>>(
        H, WT, b2, cnt, offsets, tok_list, wt_list, out);
}

// Round 5
// 366.736 us; speedup vs baseline: 2.7453x; 1.1087x over previous
//
#include <hip/hip_runtime.h>
#include <hip/hip_bf16.h>
#include <math.h>

// MoE top-2 of 8 experts. D_MODEL=1024, D_FF=4096, tokens = 2*2048 = 4096.
// R4: fix R3's workspace aliasing bug (XB overlapped H's second half — H holds
// 2*NTOK=8192 slot rows = 64MB). XB now aliases d_out (dead until gemm2):
// cvt_x -> gemm1(reads XB) -> memset(out) -> write_loss -> gemm2(accumulate).
// ws layout back to R2's proven 128.3MB footprint.

#define D_MODEL 1024
#define D_FF    4096
#define NE      8
#define NTOK    4096
#define CAP     4096

typedef __attribute__((ext_vector_type(4))) float f32x4;
typedef __attribute__((ext_vector_type(8))) short s16x8;

__device__ __forceinline__ short f2bf(float f) {
    union { float f; unsigned u; } v; v.f = f;
    unsigned r = v.u + 0x7FFFu + ((v.u >> 16) & 1u);  // RNE
    return (short)(r >> 16);
}

// async global -> LDS, 16 bytes/lane; LDS dest wave-uniform base, HW writes
// base + lane*16 (m104/m108). Global src per-lane.
__device__ __forceinline__ void gload16(const void* g, void* l) {
    __builtin_amdgcn_global_load_lds(
        (const __attribute__((address_space(1))) unsigned*)g,
        (__attribute__((address_space(3))) unsigned*)l, 16, 0, 0);
}

// ---------------- Router ----------------
__global__ __launch_bounds__(256) void router_kernel(
    const float* __restrict__ x, const float* __restrict__ gw,
    const float* __restrict__ gb,
    float* __restrict__ usage, int* __restrict__ eidx, float* __restrict__ wgt)
{
    __shared__ float s_gw[NE][D_MODEL];
    __shared__ float s_usage[NE];
    int tid = threadIdx.x;
    for (int i = tid * 4; i < NE * D_MODEL; i += 256 * 4)
        *(f32x4*)&s_gw[0][i] = *(const f32x4*)(gw + i);
    if (tid < NE) s_usage[tid] = 0.f;
    __syncthreads();

    int wid = tid >> 6, lane = tid & 63;
    int wave_stride = gridDim.x * 4;
    float l_usage[NE];
#pragma unroll
    for (int e = 0; e < NE; e++) l_usage[e] = 0.f;

    for (int t = blockIdx.x * 4 + wid; t < NTOK; t += wave_stride) {
        const float* xr = x + (size_t)t * D_MODEL;
        float acc[NE];
#pragma unroll
        for (int e = 0; e < NE; e++) acc[e] = 0.f;
        for (int i = lane * 4; i < D_MODEL; i += 64 * 4) {
            f32x4 xv = *(const f32x4*)(xr + i);
#pragma unroll
            for (int e = 0; e < NE; e++) {
                f32x4 gv = *(const f32x4*)&s_gw[e][i];
                acc[e] += xv[0]*gv[0] + xv[1]*gv[1] + xv[2]*gv[2] + xv[3]*gv[3];
            }
        }
#pragma unroll
        for (int e = 0; e < NE; e++) {
            float a = acc[e];
            for (int off = 32; off; off >>= 1) a += __shfl_down(a, off);
            acc[e] = a;
        }
        if (lane == 0) {
            float logits[NE];
            float mx = -1e30f;
#pragma unroll
            for (int e = 0; e < NE; e++) { logits[e] = acc[e] + gb[e]; mx = fmaxf(mx, logits[e]); }
            float se = 0.f;
            float pe[NE];
#pragma unroll
            for (int e = 0; e < NE; e++) { pe[e] = expf(logits[e] - mx); se += pe[e]; }
            float inv = 1.f / se;
#pragma unroll
            for (int e = 0; e < NE; e++) l_usage[e] += pe[e] * inv;
            int i0 = 0;
#pragma unroll
            for (int e = 1; e < NE; e++) if (logits[e] > logits[i0]) i0 = e;
            int i1 = -1;
#pragma unroll
            for (int e = 0; e < NE; e++) {
                if (e == i0) continue;
                if (i1 < 0 || logits[e] > logits[i1]) i1 = e;
            }
            float w0 = 1.f / (1.f + expf(logits[i1] - logits[i0]));
            eidx[t] = i0 | (i1 << 8);
            wgt[t] = w0;
        }
    }
    if (lane == 0) {
#pragma unroll
        for (int e = 0; e < NE; e++) atomicAdd(&s_usage[e], l_usage[e]);
    }
    __syncthreads();
    if (tid < NE) atomicAdd(&usage[tid], s_usage[tid]);
}

// ---------------- per-expert list compaction ----------------
__global__ __launch_bounds__(256) void build_lists(
    const int* __restrict__ eidx, const float* __restrict__ wgt,
    int* __restrict__ cnt, int* __restrict__ tok_list, float* __restrict__ wt_list)
{
    int e = blockIdx.x;
    __shared__ int s_cnt;
    if (threadIdx.x == 0) s_cnt = 0;
    __syncthreads();
    for (int t = threadIdx.x; t < NTOK; t += 256) {
        int p = eidx[t];
        float w0 = wgt[t];
        if ((p & 255) == e) {
            int s = atomicAdd(&s_cnt, 1);
            tok_list[e * CAP + s] = t; wt_list[e * CAP + s] = w0;
        }
        if ((p >> 8) == e) {
            int s = atomicAdd(&s_cnt, 1);
            tok_list[e * CAP + s] = t; wt_list[e * CAP + s] = 1.f - w0;
        }
    }
    __syncthreads();
    if (threadIdx.x == 0) cnt[e] = s_cnt;
}

// ---------------- prefix offsets (needed by gemm1) ----------------
__global__ void compute_offsets(const int* __restrict__ cnt, int* __restrict__ offsets)
{
    int o = 0;
    for (int e = 0; e < NE; e++) { offsets[e] = o; o += cnt[e]; }
}

// ---------------- load-balancing loss (after out is zeroed) ----------------
__global__ void write_loss(const float* __restrict__ usage, float* __restrict__ out_loss)
{
    float s = 0.f;
    for (int e = 0; e < NE; e++) { float u = usage[e] / (float)NTOK; s += u * u; }
    *out_loss = (float)NE * s - 1.f;
}

// ---------------- x fp32 -> bf16, one pass ----------------
__global__ __launch_bounds__(256) void cvt_x_kernel(
    const float* __restrict__ x, short* __restrict__ xb)
{
    int i = (blockIdx.x * 256 + threadIdx.x) * 8;
    f32x4 a = *(const f32x4*)(x + i);
    f32x4 b = *(const f32x4*)(x + i + 4);
    s16x8 r;
    r[0]=f2bf(a[0]); r[1]=f2bf(a[1]); r[2]=f2bf(a[2]); r[3]=f2bf(a[3]);
    r[4]=f2bf(b[0]); r[5]=f2bf(b[1]); r[6]=f2bf(b[2]); r[7]=f2bf(b[3]);
    *(s16x8*)(xb + i) = r;
}

// ---------------- transpose + cvt: src[R][C] f32 -> dst[C][R] bf16, 64x64 tiles ----
__global__ __launch_bounds__(256) void transpose_cvt(
    const float* __restrict__ src, short* __restrict__ dst, int R, int C)
{
    __shared__ float tile[64][65];
    int e = blockIdx.z;
    src += (size_t)e * R * C;
    dst += (size_t)e * R * C;
    int c0 = blockIdx.x * 64, r0 = blockIdx.y * 64;
    int tid = threadIdx.x;
    int lr = tid >> 2, lc = (tid & 3) * 16;

    const float* s = src + (size_t)(r0 + lr) * C + c0 + lc;
#pragma unroll
    for (int j = 0; j < 4; j++)
        *(f32x4*)&tile[lr][lc + j * 4] = *(const f32x4*)(s + j * 4);
    __syncthreads();

    short* d = dst + (size_t)(c0 + lr) * R + r0 + lc;
    s16x8 v0, v1;
#pragma unroll
    for (int j = 0; j < 8; j++) v0[j] = f2bf(tile[lc + j][lr]);
#pragma unroll
    for (int j = 0; j < 8; j++) v1[j] = f2bf(tile[lc + 8 + j][lr]);
    *(s16x8*)d = v0;
    *(s16x8*)(d + 8) = v1;
}

// ---------------- GEMM1: H = gelu(x_bf @ W1 + b1), 128x128 tile, BK=32 ----------------
__global__ __launch_bounds__(256) void gemm1_kernel(
    const short* __restrict__ XB, const short* __restrict__ W1T,
    const float* __restrict__ b1, const int* __restrict__ cnt,
    const int* __restrict__ offsets, const int* __restrict__ tok_list,
    short* __restrict__ H)
{
    int e  = blockIdx.y >> 5;
    int tm = blockIdx.y & 31;
    int ce = cnt[e];
    if (tm * 128 >= ce) return;
    int n0 = blockIdx.x * 128;

    __shared__ __align__(16) short As[128][32];
    __shared__ __align__(16) short Bs[128][32];

    int tid = threadIdx.x;
    int lane = tid & 63, wid = tid >> 6;
    int wr = wid >> 1, wc = wid & 1;
    int lrow = lane & 15, kgr = lane >> 4;

    int srow = wid * 16 + (lane >> 2);
    int scol = (lane & 3) * 8;
    int am0 = tm * 128 + srow, am1 = am0 + 64;
    int tok0 = tok_list[e * CAP + (am0 < ce ? am0 : 0)];
    int tok1 = tok_list[e * CAP + (am1 < ce ? am1 : 0)];
    const short* asrc0 = XB + (size_t)tok0 * D_MODEL + scol;
    const short* asrc1 = XB + (size_t)tok1 * D_MODEL + scol;
    const short* bsrc0 = W1T + ((size_t)e * D_FF + n0 + srow) * D_MODEL + scol;
    const short* bsrc1 = bsrc0 + (size_t)64 * D_MODEL;

    f32x4 acc[4][4] = {};
    for (int kt = 0; kt < D_MODEL; kt += 32) {
        gload16(asrc0 + kt, &As[wid * 16][0]);
        gload16(asrc1 + kt, &As[64 + wid * 16][0]);
        gload16(bsrc0 + kt, &Bs[wid * 16][0]);
        gload16(bsrc1 + kt, &Bs[64 + wid * 16][0]);
        __syncthreads();

        s16x8 a[4], b[4];
#pragma unroll
        for (int i = 0; i < 4; i++) {
            a[i] = *(const s16x8*)&As[wr * 64 + i * 16 + lrow][kgr * 8];
            b[i] = *(const s16x8*)&Bs[wc * 64 + i * 16 + lrow][kgr * 8];
        }
#pragma unroll
        for (int i = 0; i < 4; i++)
#pragma unroll
        for (int j = 0; j < 4; j++)
            acc[i][j] = __builtin_amdgcn_mfma_f32_16x16x32_bf16(a[i], b[j], acc[i][j], 0, 0, 0);
        __syncthreads();
    }

    int offe = offsets[e];
    float bn[4];
#pragma unroll
    for (int j = 0; j < 4; j++) bn[j] = b1[e * D_FF + n0 + wc * 64 + j * 16 + lrow];
#pragma unroll
    for (int i = 0; i < 4; i++) {
#pragma unroll
        for (int q = 0; q < 4; q++) {
            int m = tm * 128 + wr * 64 + i * 16 + kgr * 4 + q;
            if (m >= ce) continue;
            short* hrow = H + (size_t)(offe + m) * D_FF;
#pragma unroll
            for (int j = 0; j < 4; j++) {
                int n = n0 + wc * 64 + j * 16 + lrow;
                float v = acc[i][j][q] + bn[j];
                v = 0.5f * v * (1.f + erff(v * 0.70710678118654752f));  // exact gelu
                hrow[n] = f2bf(v);
            }
        }
    }
}

// ---------------- GEMM2: out[tok] += wt * (H @ W2 + b2), 128x128 tile, BK=32 ----------------
__global__ __launch_bounds__(256) void gemm2_kernel(
    const short* __restrict__ H, const short* __restrict__ W2T,
    const float* __restrict__ b2, const int* __restrict__ cnt,
    const int* __restrict__ offsets, const int* __restrict__ tok_list,
    const float* __restrict__ wt_list, float* __restrict__ out)
{
    int e  = blockIdx.y >> 5;
    int tm = blockIdx.y & 31;
    int ce = cnt[e];
    if (tm * 128 >= ce) return;
    int offe = offsets[e];
    int n0 = blockIdx.x * 128;

    __shared__ __align__(16) short As[128][32];
    __shared__ __align__(16) short Bs[128][32];

    int tid = threadIdx.x;
    int lane = tid & 63, wid = tid >> 6;
    int wr = wid >> 1, wc = wid & 1;
    int lrow = lane & 15, kgr = lane >> 4;

    int srow = wid * 16 + (lane >> 2);
    int scol = (lane & 3) * 8;
    int am0 = tm * 128 + srow, am1 = am0 + 64;
    const short* asrc0 = H + (size_t)(offe + (am0 < ce ? am0 : 0)) * D_FF + scol;
    const short* asrc1 = H + (size_t)(offe + (am1 < ce ? am1 : 0)) * D_FF + scol;
    const short* bsrc0 = W2T + ((size_t)e * D_MODEL + n0 + srow) * D_FF + scol;
    const short* bsrc1 = bsrc0 + (size_t)64 * D_FF;

    f32x4 acc[4][4] = {};
    for (int kt = 0; kt < D_FF; kt += 32) {
        gload16(asrc0 + kt, &As[wid * 16][0]);
        gload16(asrc1 + kt, &As[64 + wid * 16][0]);
        gload16(bsrc0 + kt, &Bs[wid * 16][0]);
        gload16(bsrc1 + kt, &Bs[64 + wid * 16][0]);
        __syncthreads();

        s16x8 a[4], b[4];
#pragma unroll
        for (int i = 0; i < 4; i++) {
            a[i] = *(const s16x8*)&As[wr * 64 + i * 16 + lrow][kgr * 8];
            b[i] = *(const s16x8*)&Bs[wc * 64 + i * 16 + lrow][kgr * 8];
        }
#pragma unroll
        for (int i = 0; i < 4; i++)
#pragma unroll
        for (int j = 0; j < 4; j++)
            acc[i][j] = __builtin_amdgcn_mfma_f32_16x16x32_bf16(a[i], b[j], acc[i][j], 0, 0, 0);
        __syncthreads();
    }

    float bn[4];
#pragma unroll
    for (int j = 0; j < 4; j++) bn[j] = b2[e * D_MODEL + n0 + wc * 64 + j * 16 + lrow];
#pragma unroll
    for (int i = 0; i < 4; i++) {
#pragma unroll
        for (int q = 0; q < 4; q++) {
            int m = tm * 128 + wr * 64 + i * 16 + kgr * 4 + q;
            if (m >= ce) continue;
            int tokm = tok_list[e * CAP + m];
            float wt = wt_list[e * CAP + m];
            float* orow = out + (size_t)tokm * D_MODEL;
#pragma unroll
            for (int j = 0; j < 4; j++) {
                int n = n0 + wc * 64 + j * 16 + lrow;
                atomicAdd(&orow[n], wt * (acc[i][j][q] + bn[j]));
            }
        }
    }
}

extern "C" void kernel_launch(void* const* d_in, const int* in_sizes, int n_in,
                              void* d_out, int out_size, void* d_ws, size_t ws_size,
                              hipStream_t stream)
{
    const float* x  = (const float*)d_in[0];
    const float* gw = (const float*)d_in[1];
    const float* gb = (const float*)d_in[2];
    const float* w1 = (const float*)d_in[3];
    const float* b1 = (const float*)d_in[4];
    const float* w2 = (const float*)d_in[5];
    const float* b2 = (const float*)d_in[6];
    float* out = (float*)d_out;

    // workspace layout (~128.3 MB, proven in R2)
    char* w = (char*)d_ws;
    int*   cnt      = (int*)(w + 0);
    float* usage    = (float*)(w + 32);
    int*   offsets  = (int*)(w + 64);
    int*   tok_list = (int*)(w + 128);
    float* wt_list  = (float*)(w + 128 + NE * CAP * 4);
    short* WT       = (short*)(w + 128 + 2 * NE * CAP * 4);                   // 64MB: W1T then W2T
    short* H        = (short*)((char*)WT + (size_t)NE * D_FF * D_MODEL * 2);  // 64MB: 2*NTOK slot rows
    // eidx/wgt alias WT start (dead before transpose writes WT)
    int*   eidx     = (int*)WT;
    float* wgt      = (float*)(WT + NTOK * 2);
    // XB (x as bf16, 8MB) aliases d_out — dead until the memset below
    short* XB       = (short*)d_out;

    hipMemsetAsync(d_ws, 0, 128, stream);   // cnt, usage, offsets

    router_kernel<<<256, 256, 0, stream>>>(x, gw, gb, usage, eidx, wgt);
    build_lists<<<NE, 256, 0, stream>>>(eidx, wgt, cnt, tok_list, wt_list);
    compute_offsets<<<1, 1, 0, stream>>>(cnt, offsets);
    cvt_x_kernel<<<NTOK * D_MODEL / (256 * 8), 256, 0, stream>>>(x, XB);

    // W1 [1024][4096] -> W1T [4096][1024] bf16
    transpose_cvt<<<dim3(D_FF / 64, D_MODEL / 64, NE), 256, 0, stream>>>(w1, WT, D_MODEL, D_FF);
    gemm1_kernel<<<dim3(D_FF / 128, NE * (CAP / 128)), 256, 0, stream>>>(
        XB, WT, b1, cnt, offsets, tok_list, H);

    // out is free now (gemm1 consumed XB): zero it, write loss, then accumulate
    hipMemsetAsync(d_out, 0, (size_t)out_size * sizeof(float), stream);
    write_loss<<<1, 1, 0, stream>>>(usage, out + (size_t)NTOK * D_MODEL);

    // W2 [4096][1024] -> W2T [1024][4096] bf16 (reuse WT; stream-ordered after gemm1)
    transpose_cvt<<<dim3(D_MODEL / 64, D_FF / 64, NE), 256, 0, stream>>>(w2, WT, D_FF, D_MODEL);
    gemm2_kernel<<<dim3(D_MODEL / 128, NE * (CAP / 128)), 256, 0, stream>>>(
        H, WT, b2, cnt, offsets, tok_list, wt_list, out);
}